// Round 1
// baseline (2105.151 us; speedup 1.0000x reference)
//
#include <hip/hip_runtime.h>
#include <cstdint>
#include <cstddef>

#define N_PTS   16384
#define K_CODES 8192
#define DIM     256
#define DECAYF  0.99f
#define OMDF    0.01f
#define EPSF    1e-5f

// output layout (all float32, concatenated in reference return order)
#define OFF_ZQ   0
#define OFF_LOSS 4194304
#define OFF_IDX  4194305
#define OFF_W    4210689
#define OFF_CS   6307841
#define OFF_EA   6316033
// scratch parked inside the new_weight region (overwritten last by k_neww):
//   hen  = out[OFF_W + 0 .. 8191]        (0.5*||w_k||^2)
//   keys = out[OFF_W + 8193 ...]         (u64; OFF_W+8193 is even -> 8B aligned)
#define KEYS_OFF 8193

#define TZ 32
#define TK 64
#define BK 32
#define KSPLIT 4
#define KCHUNK (K_CODES / KSPLIT)

__device__ inline unsigned long long shflxor_u64(unsigned long long v, int m, int w) {
    int lo = __shfl_xor((int)(unsigned)(v & 0xFFFFFFFFull), m, w);
    int hi = __shfl_xor((int)(unsigned)(v >> 32), m, w);
    return ((unsigned long long)(unsigned)hi << 32) | (unsigned)lo;
}

// ---- 1. init: out_ea = 0.99*ea, out_cs = 0.99*cs, loss = 0 -------------------
__global__ void k_init(const float* __restrict__ ea, const float* __restrict__ cs,
                       float* __restrict__ out) {
    int i = blockIdx.x * 256 + threadIdx.x;
    if (i < K_CODES * DIM) out[OFF_EA + i] = DECAYF * ea[i];
    if (i < K_CODES)       out[OFF_CS + i] = DECAYF * cs[i];
    if (i == 0)            out[OFF_LOSS]   = 0.0f;
}

// ---- 2. half squared norms of codebook rows ---------------------------------
__global__ void k_enorm(const float* __restrict__ w, float* __restrict__ hen) {
    int k    = blockIdx.x * 4 + (threadIdx.x >> 6);
    int lane = threadIdx.x & 63;
    float4 v = *(const float4*)(w + (size_t)k * DIM + lane * 4);
    float s  = v.x * v.x + v.y * v.y + v.z * v.z + v.w * v.w;
    #pragma unroll
    for (int m = 32; m >= 1; m >>= 1) s += __shfl_xor(s, m, 64);
    if (lane == 0) hen[k] = 0.5f * s;
}

// ---- 3. fused GEMM + argmax(z.w - 0.5||w||^2) -------------------------------
// grid = (N/TZ)*KSPLIT blocks of 128 threads. split = blockIdx%4 so each XCD
// (blockIdx%8) streams one stable 2MB W chunk (L2-resident).
__global__ __launch_bounds__(128) void k_argmin(const float* __restrict__ z,
                                                const float* __restrict__ w,
                                                float* __restrict__ out) {
    __shared__ float zs[TZ][DIM + 4];   // stride 260: 16B-aligned rows, 2-way banks
    __shared__ float wst[BK][TK + 4];   // transposed W chunk, stride 68
    __shared__ unsigned long long best[TZ];

    const float* hen = out + OFF_W;
    unsigned long long* keys = (unsigned long long*)(out + OFF_W + KEYS_OFF);

    const int tid = threadIdx.x;
    const int tx = tid & 15;   // k direction (4 codes each)
    const int ty = tid >> 4;   // z direction (4 points each)
    const int ztile = blockIdx.x >> 2;
    const int split = blockIdx.x & 3;
    const int z0 = ztile * TZ;
    const int kb = split * KCHUNK;

    // stage full z tile (32 x 256) once
    for (int i = tid; i < TZ * DIM / 4; i += 128) {
        int row = i >> 6;
        int col = (i & 63) << 2;
        *(float4*)&zs[row][col] = *(const float4*)(z + (size_t)(z0 + row) * DIM + col);
    }
    if (tid < TZ) best[tid] = 0ULL;

    for (int kt = 0; kt < KCHUNK / TK; ++kt) {
        const int k0 = kb + kt * TK;
        float acc[4][4];
        #pragma unroll
        for (int a = 0; a < 4; a++)
            #pragma unroll
            for (int b = 0; b < 4; b++) acc[a][b] = 0.f;

        for (int dc = 0; dc < DIM / BK; ++dc) {
            __syncthreads();
            // stage W chunk transposed: wst[c][r] = w[k0+r][dc*32+c]
            for (int j = tid; j < TK * BK / 4; j += 128) {
                int r  = j >> 3;
                int c4 = (j & 7) << 2;
                float4 v = *(const float4*)(w + (size_t)(k0 + r) * DIM + dc * BK + c4);
                wst[c4 + 0][r] = v.x;
                wst[c4 + 1][r] = v.y;
                wst[c4 + 2][r] = v.z;
                wst[c4 + 3][r] = v.w;
            }
            __syncthreads();
            #pragma unroll
            for (int s = 0; s < BK / 4; ++s) {
                float za[4][4], wa[4][4];
                #pragma unroll
                for (int zi = 0; zi < 4; zi++) {
                    float4 t = *(const float4*)&zs[ty * 4 + zi][dc * BK + s * 4];
                    za[zi][0] = t.x; za[zi][1] = t.y; za[zi][2] = t.z; za[zi][3] = t.w;
                }
                #pragma unroll
                for (int jj = 0; jj < 4; jj++) {
                    float4 t = *(const float4*)&wst[s * 4 + jj][tx * 4];
                    wa[jj][0] = t.x; wa[jj][1] = t.y; wa[jj][2] = t.z; wa[jj][3] = t.w;
                }
                #pragma unroll
                for (int zi = 0; zi < 4; zi++)
                    #pragma unroll
                    for (int jj = 0; jj < 4; jj++)
                        #pragma unroll
                        for (int kj = 0; kj < 4; kj++)
                            acc[zi][kj] += za[zi][jj] * wa[jj][kj];
            }
        }
        // epilogue: fold -0.5||w||^2, pack (score, K-1-k), reduce over 16 lanes
        float hv[4];
        #pragma unroll
        for (int kj = 0; kj < 4; kj++) hv[kj] = hen[k0 + tx * 4 + kj];
        #pragma unroll
        for (int zi = 0; zi < 4; zi++) {
            unsigned long long bk = 0ULL;
            #pragma unroll
            for (int kj = 0; kj < 4; kj++) {
                int kg = k0 + tx * 4 + kj;
                float sc = acc[zi][kj] - hv[kj];
                unsigned u = __float_as_uint(sc);
                u = (u & 0x80000000u) ? ~u : (u | 0x80000000u);  // order-preserving map
                unsigned long long key =
                    ((unsigned long long)u << 32) | (unsigned)(K_CODES - 1 - kg);
                if (key > bk) bk = key;
            }
            #pragma unroll
            for (int m = 8; m >= 1; m >>= 1) {
                unsigned long long o = shflxor_u64(bk, m, 16);
                if (o > bk) bk = o;
            }
            if (tx == 0 && bk > best[ty * 4 + zi]) best[ty * 4 + zi] = bk;
        }
    }
    __syncthreads();
    if (tid < TZ) keys[(size_t)split * N_PTS + z0 + tid] = best[tid];
}

// ---- 4. merge splits, gather z_q, loss, scatter EMA updates -----------------
__global__ void k_finish(const float* __restrict__ z, const float* __restrict__ w,
                         float* __restrict__ out) {
    const unsigned long long* keys =
        (const unsigned long long*)(out + OFF_W + KEYS_OFF);
    int wid  = (blockIdx.x * 256 + threadIdx.x) >> 6;
    int lane = threadIdx.x & 63;
    unsigned long long b = keys[wid];
    #pragma unroll
    for (int s = 1; s < KSPLIT; s++) {
        unsigned long long o = keys[(size_t)s * N_PTS + wid];
        if (o > b) b = o;
    }
    int idx = K_CODES - 1 - (int)(unsigned)(b & 0xFFFFFFFFull);

    float4 zv = *(const float4*)(z + (size_t)wid * DIM + lane * 4);
    float4 wv = *(const float4*)(w + (size_t)idx * DIM + lane * 4);
    *(float4*)(out + OFF_ZQ + (size_t)wid * DIM + lane * 4) = wv;  // z_q_st == z_q

    float dx = wv.x - zv.x, dy = wv.y - zv.y, dz = wv.z - zv.z, dw = wv.w - zv.w;
    float s2 = dx * dx + dy * dy + dz * dz + dw * dw;
    #pragma unroll
    for (int m = 32; m >= 1; m >>= 1) s2 += __shfl_xor(s2, m, 64);

    float* ea = out + OFF_EA + (size_t)idx * DIM + lane * 4;
    unsafeAtomicAdd(ea + 0, OMDF * zv.x);
    unsafeAtomicAdd(ea + 1, OMDF * zv.y);
    unsafeAtomicAdd(ea + 2, OMDF * zv.z);
    unsafeAtomicAdd(ea + 3, OMDF * zv.w);
    if (lane == 0) {
        out[OFF_IDX + wid] = (float)idx;
        unsafeAtomicAdd(out + OFF_LOSS, s2 * (1.0f / ((float)N_PTS * DIM)));
        unsafeAtomicAdd(out + OFF_CS + idx, OMDF);
    }
}

// ---- 5. new_weight = new_ea / ((cs+eps)/(n+K*eps)*n), one code row per block
__global__ void k_neww(float* __restrict__ out) {
    __shared__ float red[4];
    int k = blockIdx.x;
    int t = threadIdx.x;
    float p = 0.f;
    for (int j = t; j < K_CODES; j += 256) p += out[OFF_CS + j];
    #pragma unroll
    for (int m = 32; m >= 1; m >>= 1) p += __shfl_xor(p, m, 64);
    if ((t & 63) == 0) red[t >> 6] = p;
    __syncthreads();
    float n  = red[0] + red[1] + red[2] + red[3];
    float cs = out[OFF_CS + k];
    float denom = (cs + EPSF) / (n + (float)K_CODES * EPSF) * n;
    out[OFF_W + (size_t)k * DIM + t] = out[OFF_EA + (size_t)k * DIM + t] / denom;
}

extern "C" void kernel_launch(void* const* d_in, const int* in_sizes, int n_in,
                              void* d_out, int out_size, void* d_ws, size_t ws_size,
                              hipStream_t stream) {
    const float* z  = (const float*)d_in[0];
    const float* w  = (const float*)d_in[1];
    const float* cs = (const float*)d_in[2];
    const float* ea = (const float*)d_in[3];
    float* out = (float*)d_out;

    hipLaunchKernelGGL(k_init,   dim3(K_CODES * DIM / 256), dim3(256), 0, stream, ea, cs, out);
    hipLaunchKernelGGL(k_enorm,  dim3(K_CODES / 4),         dim3(256), 0, stream, w, out + OFF_W);
    hipLaunchKernelGGL(k_argmin, dim3((N_PTS / TZ) * KSPLIT), dim3(128), 0, stream, z, w, out);
    hipLaunchKernelGGL(k_finish, dim3(N_PTS / 4),           dim3(256), 0, stream, z, w, out);
    hipLaunchKernelGGL(k_neww,   dim3(K_CODES),             dim3(256), 0, stream, out);
}

// Round 2
// 547.303 us; speedup vs baseline: 3.8464x; 3.8464x over previous
//
#include <hip/hip_runtime.h>
#include <cstdint>
#include <cstddef>

#define N_PTS   16384
#define K_CODES 8192
#define DIM     256
#define DECAYF  0.99f
#define OMDF    0.01f
#define EPSF    1e-5f

// output layout (float32, concatenated in reference return order)
#define OFF_ZQ   0
#define OFF_LOSS 4194304
#define OFF_IDX  4194305
#define OFF_W    4210689
#define OFF_CS   6307841
#define OFF_EA   6316033

// scratch parked inside output regions that are written later:
//  zb  = bf16[16384*256] at out+OFF_ZQ            (8 MB)   } z_q region,
//  wb  = bf16[ 8192*256] at out+OFF_ZQ+2097152    (4 MB)   } overwritten by
//  hen = f32 [ 8192]     at out+OFF_ZQ+3145728    (32 KB)  } k_finish last
//  cand= u32 [16384*128] at out+OFF_W             (8 MB, exact fit; k_neww last)
#define ZB_OFF   OFF_ZQ
#define WB_OFF   (OFF_ZQ + 2097152)
#define HEN_OFF  (OFF_ZQ + 3145728)
#define CAND_OFF OFF_W

typedef __attribute__((ext_vector_type(8))) short bf16x8;
typedef __attribute__((ext_vector_type(4))) float f32x4;

__device__ inline unsigned long long shflxor_u64(unsigned long long v, int m) {
    int lo = __shfl_xor((int)(unsigned)(v & 0xFFFFFFFFull), m, 64);
    int hi = __shfl_xor((int)(unsigned)(v >> 32), m, 64);
    return ((unsigned long long)(unsigned)hi << 32) | (unsigned)lo;
}

__device__ inline unsigned short f2b(float f) {  // fp32 -> bf16 bits, RNE
    unsigned u = __float_as_uint(f);
    return (unsigned short)((u + 0x7FFFu + ((u >> 16) & 1u)) >> 16);
}

__device__ inline unsigned ordmap(float f) {     // order-preserving fp32->u32
    unsigned u = __float_as_uint(f);
    return (u & 0x80000000u) ? ~u : (u | 0x80000000u);
}

__device__ inline float orddec(unsigned v) {     // inverse (low 13 bits trashed)
    v &= 0xFFFFE000u;
    return (v & 0x80000000u) ? __uint_as_float(v & 0x7FFFFFFFu)
                             : __uint_as_float(~v);
}

__device__ inline void gload16(const void* g, void* l) {
    __builtin_amdgcn_global_load_lds(
        (const __attribute__((address_space(1))) unsigned int*)g,
        (__attribute__((address_space(3))) unsigned int*)l, 16, 0, 0);
}

// ---- 1. init: out_ea = 0.99*ea, out_cs = 0.99*cs, loss = 0 ------------------
__global__ void k_init(const float* __restrict__ ea, const float* __restrict__ cs,
                       float* __restrict__ out) {
    int i = blockIdx.x * 256 + threadIdx.x;
    if (i < K_CODES * DIM) out[OFF_EA + i] = DECAYF * ea[i];
    if (i < K_CODES)       out[OFF_CS + i] = DECAYF * cs[i];
    if (i == 0)            out[OFF_LOSS]   = 0.0f;
}

// ---- 2. fp32 -> bf16 conversion (8 elems/thread) ----------------------------
__global__ void k_cvt(const float* __restrict__ src, short* __restrict__ dst) {
    size_t base = (size_t)(blockIdx.x * 256 + threadIdx.x) * 8;
    float4 a = *(const float4*)(src + base);
    float4 b = *(const float4*)(src + base + 4);
    bf16x8 o;
    o[0] = (short)f2b(a.x); o[1] = (short)f2b(a.y);
    o[2] = (short)f2b(a.z); o[3] = (short)f2b(a.w);
    o[4] = (short)f2b(b.x); o[5] = (short)f2b(b.y);
    o[6] = (short)f2b(b.z); o[7] = (short)f2b(b.w);
    *(bf16x8*)(dst + base) = o;
}

// ---- 3. half squared norms of codebook rows ---------------------------------
__global__ void k_enorm(const float* __restrict__ w, float* __restrict__ hen) {
    int k    = blockIdx.x * 4 + (threadIdx.x >> 6);
    int lane = threadIdx.x & 63;
    float4 v = *(const float4*)(w + (size_t)k * DIM + lane * 4);
    float s  = v.x * v.x + v.y * v.y + v.z * v.z + v.w * v.w;
    #pragma unroll
    for (int m = 32; m >= 1; m >>= 1) s += __shfl_xor(s, m, 64);
    if (lane == 0) hen[k] = 0.5f * s;
}

// ---- 4. bf16 MFMA GEMM + top-2 candidates per (z, 128-code tile) ------------
// 128x128 tile, 256 threads = 4 waves (2x2 of 64x64), BK=64, 16x16x32 MFMA.
__global__ __launch_bounds__(256) void k_gemm(const short* __restrict__ zb,
                                              const short* __restrict__ wb,
                                              const float* __restrict__ hen,
                                              unsigned* __restrict__ cand) {
    __shared__ __align__(16) short smem[16384];          // 32 KB: As|Bs
    short* As = smem;
    short* Bs = smem + 8192;
    unsigned long long* tbuf = (unsigned long long*)smem; // reused in epilogue

    const int tid  = threadIdx.x;
    const int lane = tid & 63;
    const int wv   = tid >> 6;
    const int wm   = wv >> 1, wn = wv & 1;
    const int ztile = blockIdx.x & 127;      // kt-major: 128 blocks share B-tile
    const int kt    = blockIdx.x >> 7;
    const int z0 = ztile * 128, k0 = kt * 128;

    f32x4 acc[4][4];
    #pragma unroll
    for (int i = 0; i < 4; i++)
        #pragma unroll
        for (int j = 0; j < 4; j++) acc[i][j] = (f32x4){0.f, 0.f, 0.f, 0.f};

    const int srow = lane >> 3;          // staging: row within 8-row segment
    const int scol = (lane & 7) * 8;     // col (bf16) within 64-col chunk

    for (int dc = 0; dc < 4; ++dc) {
        __syncthreads();
        #pragma unroll
        for (int s4 = 0; s4 < 4; ++s4) {
            int seg = wv * 4 + s4;       // 16 segments of 8 rows x 64 cols
            gload16(zb + (size_t)(z0 + seg * 8 + srow) * DIM + dc * 64 + scol,
                    As + seg * 512 + lane * 8);
            gload16(wb + (size_t)(k0 + seg * 8 + srow) * DIM + dc * 64 + scol,
                    Bs + seg * 512 + lane * 8);
        }
        __syncthreads();
        #pragma unroll
        for (int kk = 0; kk < 2; ++kk) {
            bf16x8 af[4], bfr[4];
            #pragma unroll
            for (int mi = 0; mi < 4; mi++)
                af[mi] = *(const bf16x8*)&As[(wm * 64 + mi * 16 + (lane & 15)) * 64
                                             + kk * 32 + (lane >> 4) * 8];
            #pragma unroll
            for (int ni = 0; ni < 4; ni++)
                bfr[ni] = *(const bf16x8*)&Bs[(wn * 64 + ni * 16 + (lane & 15)) * 64
                                              + kk * 32 + (lane >> 4) * 8];
            #pragma unroll
            for (int mi = 0; mi < 4; mi++)
                #pragma unroll
                for (int ni = 0; ni < 4; ni++)
                    acc[mi][ni] = __builtin_amdgcn_mfma_f32_16x16x32_bf16(
                        af[mi], bfr[ni], acc[mi][ni], 0, 0, 0);
        }
    }

    float h[4];
    #pragma unroll
    for (int ni = 0; ni < 4; ni++) h[ni] = hen[k0 + wn * 64 + ni * 16 + (lane & 15)];
    __syncthreads();   // smem -> tbuf reuse

    #pragma unroll
    for (int mi = 0; mi < 4; mi++) {
        #pragma unroll
        for (int r = 0; r < 4; r++) {
            unsigned long long t1 = 0ULL, t2 = 0ULL;
            #pragma unroll
            for (int ni = 0; ni < 4; ni++) {
                int kg = k0 + wn * 64 + ni * 16 + (lane & 15);
                float sc = acc[mi][ni][r] - h[ni];
                unsigned long long key = ((unsigned long long)ordmap(sc) << 32)
                                       | (unsigned)(K_CODES - 1 - kg);
                if (key > t1) { t2 = t1; t1 = key; }
                else if (key > t2) t2 = key;
            }
            // butterfly top-2 merge over the 16 col-lanes of this quad
            #pragma unroll
            for (int m = 8; m >= 1; m >>= 1) {
                unsigned long long b1 = shflxor_u64(t1, m);
                unsigned long long b2 = shflxor_u64(t2, m);
                unsigned long long hi = t1 >= b1 ? t1 : b1;
                unsigned long long lo = t1 >= b1 ? b1 : t1;
                unsigned long long se = t1 >= b1 ? t2 : b2;
                t1 = hi; t2 = lo >= se ? lo : se;
            }
            if ((lane & 15) == 0) {
                int row = wm * 64 + mi * 16 + (lane >> 4) * 4 + r;
                tbuf[row * 4 + wn * 2 + 0] = t1;
                tbuf[row * 4 + wn * 2 + 1] = t2;
            }
        }
    }
    __syncthreads();
    if (tid < 128) {
        unsigned long long a1 = tbuf[tid * 4 + 0], a2 = tbuf[tid * 4 + 1];
        unsigned long long b1 = tbuf[tid * 4 + 2], b2 = tbuf[tid * 4 + 3];
        unsigned long long hi = a1 >= b1 ? a1 : b1;
        unsigned long long lo = a1 >= b1 ? b1 : a1;
        unsigned long long se = a1 >= b1 ? a2 : b2;
        a1 = hi; a2 = lo >= se ? lo : se;
        unsigned i1 = (unsigned)(K_CODES - 1) - (unsigned)a1;
        unsigned i2 = (unsigned)(K_CODES - 1) - (unsigned)a2;
        cand[(size_t)(z0 + tid) * 128 + kt * 2 + 0] =
            ((unsigned)(a1 >> 32) & 0xFFFFE000u) | i1;
        cand[(size_t)(z0 + tid) * 128 + kt * 2 + 1] =
            ((unsigned)(a2 >> 32) & 0xFFFFE000u) | i2;
    }
}

// ---- 5. fp32 rescore of near-best candidates, exact argmin ------------------
// one wave per z-point
__global__ void k_rescore(const float* __restrict__ z, const float* __restrict__ w,
                          const float* __restrict__ hen,
                          const unsigned* __restrict__ cand,
                          float* __restrict__ out) {
    int wid  = (blockIdx.x * 256 + threadIdx.x) >> 6;
    int lane = threadIdx.x & 63;
    float4 zv = *(const float4*)(z + (size_t)wid * DIM + lane * 4);
    uint2 cw  = *(const uint2*)(cand + (size_t)wid * 128 + lane * 2);

    unsigned mx = cw.x > cw.y ? cw.x : cw.y;
    #pragma unroll
    for (int m = 32; m >= 1; m >>= 1) {
        unsigned o = (unsigned)__shfl_xor((int)mx, m, 64);
        if (o > mx) mx = o;
    }
    float thr = orddec(mx) - 0.75f;   // covers bf16 score error (~6.6 sigma)

    unsigned long long best = 0ULL;
    #pragma unroll
    for (int j = 0; j < 2; j++) {
        unsigned cj = j ? cw.y : cw.x;
        unsigned long long mask = __ballot(orddec(cj) >= thr);
        while (mask) {
            int l = __ffsll((unsigned long long)mask) - 1;
            mask &= mask - 1;
            unsigned cwd = (unsigned)__shfl((int)cj, l, 64);
            int k = (int)(cwd & 0x1FFFu);
            float4 wv = *(const float4*)(w + (size_t)k * DIM + lane * 4);
            float s = zv.x * wv.x + zv.y * wv.y + zv.z * wv.z + zv.w * wv.w;
            #pragma unroll
            for (int m = 32; m >= 1; m >>= 1) s += __shfl_xor(s, m, 64);
            float sc = s - hen[k];
            unsigned long long key = ((unsigned long long)ordmap(sc) << 32)
                                   | (unsigned)(K_CODES - 1 - k);
            if (key > best) best = key;
        }
    }
    if (lane == 0)
        out[OFF_IDX + wid] = (float)(K_CODES - 1 - (unsigned)(best & 0xFFFFFFFFull));
}

// ---- 6. gather z_q, loss, scatter EMA updates (one wave per z) --------------
__global__ void k_finish(const float* __restrict__ z, const float* __restrict__ w,
                         float* __restrict__ out) {
    int wid  = (blockIdx.x * 256 + threadIdx.x) >> 6;
    int lane = threadIdx.x & 63;
    int idx  = (int)out[OFF_IDX + wid];

    float4 zv = *(const float4*)(z + (size_t)wid * DIM + lane * 4);
    float4 wv = *(const float4*)(w + (size_t)idx * DIM + lane * 4);
    *(float4*)(out + OFF_ZQ + (size_t)wid * DIM + lane * 4) = wv;

    float dx = wv.x - zv.x, dy = wv.y - zv.y, dz = wv.z - zv.z, dw = wv.w - zv.w;
    float s2 = dx * dx + dy * dy + dz * dz + dw * dw;
    #pragma unroll
    for (int m = 32; m >= 1; m >>= 1) s2 += __shfl_xor(s2, m, 64);

    float* ea = out + OFF_EA + (size_t)idx * DIM + lane * 4;
    unsafeAtomicAdd(ea + 0, OMDF * zv.x);
    unsafeAtomicAdd(ea + 1, OMDF * zv.y);
    unsafeAtomicAdd(ea + 2, OMDF * zv.z);
    unsafeAtomicAdd(ea + 3, OMDF * zv.w);
    if (lane == 0) {
        unsafeAtomicAdd(out + OFF_LOSS, s2 * (1.0f / ((float)N_PTS * DIM)));
        unsafeAtomicAdd(out + OFF_CS + idx, OMDF);
    }
}

// ---- 7. new_weight = new_ea / ((cs+eps)/(n+K*eps)*n) ------------------------
__global__ void k_neww(float* __restrict__ out) {
    __shared__ float red[4];
    int k = blockIdx.x;
    int t = threadIdx.x;
    float p = 0.f;
    for (int j = t; j < K_CODES; j += 256) p += out[OFF_CS + j];
    #pragma unroll
    for (int m = 32; m >= 1; m >>= 1) p += __shfl_xor(p, m, 64);
    if ((t & 63) == 0) red[t >> 6] = p;
    __syncthreads();
    float n  = red[0] + red[1] + red[2] + red[3];
    float cs = out[OFF_CS + k];
    float denom = (cs + EPSF) / (n + (float)K_CODES * EPSF) * n;
    out[OFF_W + (size_t)k * DIM + t] = out[OFF_EA + (size_t)k * DIM + t] / denom;
}

extern "C" void kernel_launch(void* const* d_in, const int* in_sizes, int n_in,
                              void* d_out, int out_size, void* d_ws, size_t ws_size,
                              hipStream_t stream) {
    const float* z  = (const float*)d_in[0];
    const float* w  = (const float*)d_in[1];
    const float* cs = (const float*)d_in[2];
    const float* ea = (const float*)d_in[3];
    float* out = (float*)d_out;

    short*    zb   = (short*)(out + ZB_OFF);
    short*    wb   = (short*)(out + WB_OFF);
    float*    hen  = out + HEN_OFF;
    unsigned* cand = (unsigned*)(out + CAND_OFF);

    hipLaunchKernelGGL(k_init,    dim3(K_CODES * DIM / 256), dim3(256), 0, stream, ea, cs, out);
    hipLaunchKernelGGL(k_cvt,     dim3(N_PTS * DIM / 2048),  dim3(256), 0, stream, z, zb);
    hipLaunchKernelGGL(k_cvt,     dim3(K_CODES * DIM / 2048),dim3(256), 0, stream, w, wb);
    hipLaunchKernelGGL(k_enorm,   dim3(K_CODES / 4),         dim3(256), 0, stream, w, hen);
    hipLaunchKernelGGL(k_gemm,    dim3((N_PTS / 128) * (K_CODES / 128)), dim3(256), 0, stream,
                       zb, wb, hen, cand);
    hipLaunchKernelGGL(k_rescore, dim3(N_PTS / 4),           dim3(256), 0, stream,
                       z, w, hen, cand, out);
    hipLaunchKernelGGL(k_finish,  dim3(N_PTS / 4),           dim3(256), 0, stream, z, w, out);
    hipLaunchKernelGGL(k_neww,    dim3(K_CODES),             dim3(256), 0, stream, out);
}

// Round 3
// 380.900 us; speedup vs baseline: 5.5268x; 1.4369x over previous
//
#include <hip/hip_runtime.h>
#include <cstdint>
#include <cstddef>

#define N_PTS   16384
#define K_CODES 8192
#define DIM     256
#define DECAYF  0.99f
#define OMDF    0.01f
#define EPSF    1e-5f

// output layout (float32, concatenated in reference return order)
#define OFF_ZQ   0
#define OFF_LOSS 4194304
#define OFF_IDX  4194305
#define OFF_W    4210689
#define OFF_CS   6307841
#define OFF_EA   6316033

// scratch parked inside output regions that are written later:
//  zb  = bf16[16384*256] at out+OFF_ZQ            (8 MB)   } z_q region, dead
//  wb  = bf16[ 8192*256] at out+OFF_ZQ+2097152    (4 MB)   } after k_gemm;
//  hen = f32 [ 8192]     at out+OFF_ZQ+3145728    (32 KB)  } k_rescore rewrites
//  cand= u32 [16384*128] at out+OFF_W             (8 MB, exact fit; k_gather last)
#define ZB_OFF   OFF_ZQ
#define WB_OFF   (OFF_ZQ + 2097152)
#define HEN_OFF  (OFF_ZQ + 3145728)
#define CAND_OFF OFF_W

typedef __attribute__((ext_vector_type(8))) short bf16x8;
typedef __attribute__((ext_vector_type(4))) float f32x4;

__device__ inline unsigned long long shflxor_u64(unsigned long long v, int m) {
    int lo = __shfl_xor((int)(unsigned)(v & 0xFFFFFFFFull), m, 64);
    int hi = __shfl_xor((int)(unsigned)(v >> 32), m, 64);
    return ((unsigned long long)(unsigned)hi << 32) | (unsigned)lo;
}

__device__ inline unsigned short f2b(float f) {  // fp32 -> bf16 bits, RNE
    unsigned u = __float_as_uint(f);
    return (unsigned short)((u + 0x7FFFu + ((u >> 16) & 1u)) >> 16);
}

__device__ inline unsigned ordmap(float f) {     // order-preserving fp32->u32
    unsigned u = __float_as_uint(f);
    return (u & 0x80000000u) ? ~u : (u | 0x80000000u);
}

__device__ inline float orddec(unsigned v) {     // inverse (low 13 bits trashed)
    v &= 0xFFFFE000u;
    return (v & 0x80000000u) ? __uint_as_float(v & 0x7FFFFFFFu)
                             : __uint_as_float(~v);
}

__device__ inline void gload16(const void* g, void* l) {
    __builtin_amdgcn_global_load_lds(
        (const __attribute__((address_space(1))) unsigned int*)g,
        (__attribute__((address_space(3))) unsigned int*)l, 16, 0, 0);
}

// ---- 1. fp32 -> bf16 conversion (8 elems/thread) ----------------------------
__global__ void k_cvt(const float* __restrict__ src, short* __restrict__ dst) {
    size_t base = (size_t)(blockIdx.x * 256 + threadIdx.x) * 8;
    float4 a = *(const float4*)(src + base);
    float4 b = *(const float4*)(src + base + 4);
    bf16x8 o;
    o[0] = (short)f2b(a.x); o[1] = (short)f2b(a.y);
    o[2] = (short)f2b(a.z); o[3] = (short)f2b(a.w);
    o[4] = (short)f2b(b.x); o[5] = (short)f2b(b.y);
    o[6] = (short)f2b(b.z); o[7] = (short)f2b(b.w);
    *(bf16x8*)(dst + base) = o;
}

// ---- 2. half squared norms of codebook rows (for the bf16 GEMM epilogue) ----
__global__ void k_enorm(const float* __restrict__ w, float* __restrict__ hen) {
    int k    = blockIdx.x * 4 + (threadIdx.x >> 6);
    int lane = threadIdx.x & 63;
    float4 v = *(const float4*)(w + (size_t)k * DIM + lane * 4);
    float s  = v.x * v.x + v.y * v.y + v.z * v.z + v.w * v.w;
    #pragma unroll
    for (int m = 32; m >= 1; m >>= 1) s += __shfl_xor(s, m, 64);
    if (lane == 0) hen[k] = 0.5f * s;
}

// ---- 3. zero the per-code counters (ws is poisoned each launch) -------------
__global__ void k_zero(unsigned* __restrict__ cnt) {
    int i = blockIdx.x * 256 + threadIdx.x;
    if (i < K_CODES) cnt[i] = 0u;
}

// ---- 4. bf16 MFMA GEMM + top-2 candidates per (z, 128-code tile) ------------
__global__ __launch_bounds__(256) void k_gemm(const short* __restrict__ zb,
                                              const short* __restrict__ wb,
                                              const float* __restrict__ hen,
                                              unsigned* __restrict__ cand) {
    __shared__ __align__(16) short smem[16384];          // 32 KB: As|Bs
    short* As = smem;
    short* Bs = smem + 8192;
    unsigned long long* tbuf = (unsigned long long*)smem; // reused in epilogue

    const int tid  = threadIdx.x;
    const int lane = tid & 63;
    const int wv   = tid >> 6;
    const int wm   = wv >> 1, wn = wv & 1;
    const int ztile = blockIdx.x & 127;      // kt-major: 128 blocks share B-tile
    const int kt    = blockIdx.x >> 7;
    const int z0 = ztile * 128, k0 = kt * 128;

    f32x4 acc[4][4];
    #pragma unroll
    for (int i = 0; i < 4; i++)
        #pragma unroll
        for (int j = 0; j < 4; j++) acc[i][j] = (f32x4){0.f, 0.f, 0.f, 0.f};

    const int srow = lane >> 3;
    const int scol = (lane & 7) * 8;

    for (int dc = 0; dc < 4; ++dc) {
        __syncthreads();
        #pragma unroll
        for (int s4 = 0; s4 < 4; ++s4) {
            int seg = wv * 4 + s4;
            gload16(zb + (size_t)(z0 + seg * 8 + srow) * DIM + dc * 64 + scol,
                    As + seg * 512 + lane * 8);
            gload16(wb + (size_t)(k0 + seg * 8 + srow) * DIM + dc * 64 + scol,
                    Bs + seg * 512 + lane * 8);
        }
        __syncthreads();
        #pragma unroll
        for (int kk = 0; kk < 2; ++kk) {
            bf16x8 af[4], bfr[4];
            #pragma unroll
            for (int mi = 0; mi < 4; mi++)
                af[mi] = *(const bf16x8*)&As[(wm * 64 + mi * 16 + (lane & 15)) * 64
                                             + kk * 32 + (lane >> 4) * 8];
            #pragma unroll
            for (int ni = 0; ni < 4; ni++)
                bfr[ni] = *(const bf16x8*)&Bs[(wn * 64 + ni * 16 + (lane & 15)) * 64
                                              + kk * 32 + (lane >> 4) * 8];
            #pragma unroll
            for (int mi = 0; mi < 4; mi++)
                #pragma unroll
                for (int ni = 0; ni < 4; ni++)
                    acc[mi][ni] = __builtin_amdgcn_mfma_f32_16x16x32_bf16(
                        af[mi], bfr[ni], acc[mi][ni], 0, 0, 0);
        }
    }

    float h[4];
    #pragma unroll
    for (int ni = 0; ni < 4; ni++) h[ni] = hen[k0 + wn * 64 + ni * 16 + (lane & 15)];
    __syncthreads();

    #pragma unroll
    for (int mi = 0; mi < 4; mi++) {
        #pragma unroll
        for (int r = 0; r < 4; r++) {
            unsigned long long t1 = 0ULL, t2 = 0ULL;
            #pragma unroll
            for (int ni = 0; ni < 4; ni++) {
                int kg = k0 + wn * 64 + ni * 16 + (lane & 15);
                float sc = acc[mi][ni][r] - h[ni];
                unsigned long long key = ((unsigned long long)ordmap(sc) << 32)
                                       | (unsigned)(K_CODES - 1 - kg);
                if (key > t1) { t2 = t1; t1 = key; }
                else if (key > t2) t2 = key;
            }
            #pragma unroll
            for (int m = 8; m >= 1; m >>= 1) {
                unsigned long long b1 = shflxor_u64(t1, m);
                unsigned long long b2 = shflxor_u64(t2, m);
                unsigned long long hi = t1 >= b1 ? t1 : b1;
                unsigned long long lo = t1 >= b1 ? b1 : t1;
                unsigned long long se = t1 >= b1 ? t2 : b2;
                t1 = hi; t2 = lo >= se ? lo : se;
            }
            if ((lane & 15) == 0) {
                int row = wm * 64 + mi * 16 + (lane >> 4) * 4 + r;
                tbuf[row * 4 + wn * 2 + 0] = t1;
                tbuf[row * 4 + wn * 2 + 1] = t2;
            }
        }
    }
    __syncthreads();
    if (tid < 128) {
        unsigned long long a1 = tbuf[tid * 4 + 0], a2 = tbuf[tid * 4 + 1];
        unsigned long long b1 = tbuf[tid * 4 + 2], b2 = tbuf[tid * 4 + 3];
        unsigned long long hi = a1 >= b1 ? a1 : b1;
        unsigned long long lo = a1 >= b1 ? b1 : a1;
        unsigned long long se = a1 >= b1 ? a2 : b2;
        a1 = hi; a2 = lo >= se ? lo : se;
        unsigned i1 = (unsigned)(K_CODES - 1) - (unsigned)a1;
        unsigned i2 = (unsigned)(K_CODES - 1) - (unsigned)a2;
        cand[(size_t)(z0 + tid) * 128 + kt * 2 + 0] =
            ((unsigned)(a1 >> 32) & 0xFFFFE000u) | i1;
        cand[(size_t)(z0 + tid) * 128 + kt * 2 + 1] =
            ((unsigned)(a2 >> 32) & 0xFFFFE000u) | i2;
    }
}

// ---- 5. fp32 rescore + idx + z_q gather + loss partial + count --------------
// one wave per z-point; hen recomputed inline from the w rows we load anyway
__global__ void k_rescore(const float* __restrict__ z, const float* __restrict__ w,
                          const unsigned* __restrict__ cand,
                          float* __restrict__ out,
                          unsigned* __restrict__ cnt, float* __restrict__ lossp) {
    int wid  = (blockIdx.x * 256 + threadIdx.x) >> 6;
    int lane = threadIdx.x & 63;
    float4 zv = *(const float4*)(z + (size_t)wid * DIM + lane * 4);
    uint2 cw  = *(const uint2*)(cand + (size_t)wid * 128 + lane * 2);

    unsigned mx = cw.x > cw.y ? cw.x : cw.y;
    #pragma unroll
    for (int m = 32; m >= 1; m >>= 1) {
        unsigned o = (unsigned)__shfl_xor((int)mx, m, 64);
        if (o > mx) mx = o;
    }
    float thr = orddec(mx) - 0.75f;   // covers bf16 score error (~6.6 sigma)

    unsigned long long best = 0ULL;
    #pragma unroll
    for (int j = 0; j < 2; j++) {
        unsigned cj = j ? cw.y : cw.x;
        unsigned long long mask = __ballot(orddec(cj) >= thr);
        while (mask) {
            int l = __ffsll((unsigned long long)mask) - 1;
            mask &= mask - 1;
            unsigned cwd = (unsigned)__shfl((int)cj, l, 64);
            int k = (int)(cwd & 0x1FFFu);
            float4 wv = *(const float4*)(w + (size_t)k * DIM + lane * 4);
            float s = zv.x * wv.x + zv.y * wv.y + zv.z * wv.z + zv.w * wv.w;
            float h = wv.x * wv.x + wv.y * wv.y + wv.z * wv.z + wv.w * wv.w;
            #pragma unroll
            for (int m = 32; m >= 1; m >>= 1) {
                s += __shfl_xor(s, m, 64);
                h += __shfl_xor(h, m, 64);
            }
            float sc = s - 0.5f * h;
            unsigned long long key = ((unsigned long long)ordmap(sc) << 32)
                                   | (unsigned)(K_CODES - 1 - k);
            if (key > best) best = key;
        }
    }
    int idx = K_CODES - 1 - (int)(unsigned)(best & 0xFFFFFFFFull);

    float4 wv = *(const float4*)(w + (size_t)idx * DIM + lane * 4);
    *(float4*)(out + OFF_ZQ + (size_t)wid * DIM + lane * 4) = wv;

    float dx = wv.x - zv.x, dy = wv.y - zv.y, dz = wv.z - zv.z, dw = wv.w - zv.w;
    float s2 = dx * dx + dy * dy + dz * dz + dw * dw;
    #pragma unroll
    for (int m = 32; m >= 1; m >>= 1) s2 += __shfl_xor(s2, m, 64);

    if (lane == 0) {
        out[OFF_IDX + wid] = (float)idx;
        lossp[wid] = s2;
        atomicAdd(cnt + idx, 1u);
    }
}

// ---- 6. single-block scan: offsets, cursor, new_cs, n, loss -----------------
__global__ __launch_bounds__(1024) void k_prefix(const float* __restrict__ csin,
                                                 float* __restrict__ out,
                                                 const unsigned* __restrict__ cnt,
                                                 unsigned* __restrict__ cursor,
                                                 unsigned* __restrict__ offs,
                                                 const float* __restrict__ lossp,
                                                 float* __restrict__ nval) {
    __shared__ unsigned wtot[16], wbase[16];
    __shared__ float fred[16], fred2[16];
    int t = threadIdx.x, lane = t & 63, wv = t >> 6;
    int base = t * 8;
    unsigned c[8], mysum = 0;
    #pragma unroll
    for (int i = 0; i < 8; i++) { c[i] = cnt[base + i]; mysum += c[i]; }
    unsigned inc = mysum;
    #pragma unroll
    for (int off = 1; off < 64; off <<= 1) {
        unsigned v = (unsigned)__shfl_up((int)inc, off, 64);
        if (lane >= off) inc += v;
    }
    if (lane == 63) wtot[wv] = inc;
    __syncthreads();
    if (t == 0) {
        unsigned r = 0;
        for (int i = 0; i < 16; i++) { wbase[i] = r; r += wtot[i]; }
        offs[K_CODES] = r;
    }
    __syncthreads();
    unsigned my0 = wbase[wv] + inc - mysum;
    float csl = 0.f;
    #pragma unroll
    for (int i = 0; i < 8; i++) {
        offs[base + i]   = my0;
        cursor[base + i] = my0;
        my0 += c[i];
        float ncs = DECAYF * csin[base + i] + OMDF * (float)c[i];
        out[OFF_CS + base + i] = ncs;
        csl += ncs;
    }
    #pragma unroll
    for (int m = 32; m >= 1; m >>= 1) csl += __shfl_xor(csl, m, 64);
    if (lane == 0) fred[wv] = csl;
    float lp = 0.f;
    #pragma unroll
    for (int i = 0; i < 16; i++) lp += lossp[t + i * 1024];
    #pragma unroll
    for (int m = 32; m >= 1; m >>= 1) lp += __shfl_xor(lp, m, 64);
    if (lane == 0) fred2[wv] = lp;
    __syncthreads();
    if (t == 0) {
        float n = 0.f, L = 0.f;
        for (int i = 0; i < 16; i++) { n += fred[i]; L += fred2[i]; }
        *nval = n;
        out[OFF_LOSS] = L * (1.0f / ((float)N_PTS * DIM));
    }
}

// ---- 7. fill per-code point lists -------------------------------------------
__global__ void k_fill(const float* __restrict__ out,
                       unsigned* __restrict__ cursor, unsigned* __restrict__ list) {
    int i = blockIdx.x * 256 + threadIdx.x;
    int idx = (int)out[OFF_IDX + i];
    unsigned pos = atomicAdd(cursor + idx, 1u);
    list[pos] = (unsigned)i;
}

// ---- 8. per-code gather: new_ea and new_weight rows (no atomics) ------------
__global__ void k_gather(const float* __restrict__ z, const float* __restrict__ ea,
                         float* __restrict__ out,
                         const unsigned* __restrict__ offs,
                         const unsigned* __restrict__ list,
                         const float* __restrict__ nval) {
    int k = blockIdx.x, lane = threadIdx.x;
    unsigned beg = offs[k], end = offs[k + 1];
    float4 acc = {0.f, 0.f, 0.f, 0.f};
    for (unsigned p = beg; p < end; ++p) {
        unsigned i = list[p];
        float4 zv = *(const float4*)(z + (size_t)i * DIM + lane * 4);
        acc.x += zv.x; acc.y += zv.y; acc.z += zv.z; acc.w += zv.w;
    }
    float4 e = *(const float4*)(ea + (size_t)k * DIM + lane * 4);
    e.x = DECAYF * e.x + OMDF * acc.x;
    e.y = DECAYF * e.y + OMDF * acc.y;
    e.z = DECAYF * e.z + OMDF * acc.z;
    e.w = DECAYF * e.w + OMDF * acc.w;
    *(float4*)(out + OFF_EA + (size_t)k * DIM + lane * 4) = e;

    float cs = out[OFF_CS + k];
    float n  = *nval;
    float inv = 1.f / ((cs + EPSF) / (n + (float)K_CODES * EPSF) * n);
    float4 wr = {e.x * inv, e.y * inv, e.z * inv, e.w * inv};
    *(float4*)(out + OFF_W + (size_t)k * DIM + lane * 4) = wr;
}

extern "C" void kernel_launch(void* const* d_in, const int* in_sizes, int n_in,
                              void* d_out, int out_size, void* d_ws, size_t ws_size,
                              hipStream_t stream) {
    const float* z  = (const float*)d_in[0];
    const float* w  = (const float*)d_in[1];
    const float* cs = (const float*)d_in[2];
    const float* ea = (const float*)d_in[3];
    float* out = (float*)d_out;

    short*    zb   = (short*)(out + ZB_OFF);
    short*    wb   = (short*)(out + WB_OFF);
    float*    hen  = out + HEN_OFF;
    unsigned* cand = (unsigned*)(out + CAND_OFF);

    // small scratch in d_ws (~230 KB)
    unsigned* cnt    = (unsigned*)d_ws;        // 8192
    unsigned* cursor = cnt + 8192;             // 8192
    unsigned* offs   = cursor + 8192;          // 8193 (padded to 8200)
    unsigned* list   = offs + 8200;            // 16384
    float*    lossp  = (float*)(list + 16384); // 16384
    float*    nval   = lossp + 16384;          // 1

    hipLaunchKernelGGL(k_cvt,     dim3(N_PTS * DIM / 2048),   dim3(256), 0, stream, z, zb);
    hipLaunchKernelGGL(k_cvt,     dim3(K_CODES * DIM / 2048), dim3(256), 0, stream, w, wb);
    hipLaunchKernelGGL(k_enorm,   dim3(K_CODES / 4),          dim3(256), 0, stream, w, hen);
    hipLaunchKernelGGL(k_zero,    dim3(32),                   dim3(256), 0, stream, cnt);
    hipLaunchKernelGGL(k_gemm,    dim3((N_PTS / 128) * (K_CODES / 128)), dim3(256), 0, stream,
                       zb, wb, hen, cand);
    hipLaunchKernelGGL(k_rescore, dim3(N_PTS / 4),            dim3(256), 0, stream,
                       z, w, cand, out, cnt, lossp);
    hipLaunchKernelGGL(k_prefix,  dim3(1),                    dim3(1024), 0, stream,
                       cs, out, cnt, cursor, offs, lossp, nval);
    hipLaunchKernelGGL(k_fill,    dim3(N_PTS / 256),          dim3(256), 0, stream,
                       out, cursor, list);
    hipLaunchKernelGGL(k_gather,  dim3(K_CODES),              dim3(64), 0, stream,
                       z, ea, out, offs, list, nval);
}

// Round 4
// 303.313 us; speedup vs baseline: 6.9405x; 1.2558x over previous
//
#include <hip/hip_runtime.h>
#include <cstdint>
#include <cstddef>

#define N_PTS   16384
#define K_CODES 8192
#define DIM     256
#define DECAYF  0.99f
#define OMDF    0.01f
#define EPSF    1e-5f

// output layout (float32, concatenated in reference return order)
#define OFF_ZQ   0
#define OFF_LOSS 4194304
#define OFF_IDX  4194305
#define OFF_W    4210689
#define OFF_CS   6307841
#define OFF_EA   6316033

// scratch parked inside output regions that are written later:
//  zb  = bf16[16384*256] at out+OFF_ZQ            (8 MB)   } z_q region, dead
//  wb  = bf16[ 8192*256] at out+OFF_ZQ+2097152    (4 MB)   } after k_gemm;
//  hen = f32 [ 8192]     at out+OFF_ZQ+3145728    (32 KB)  } k_rescore rewrites
//  cand= u32 [16384*128] at out+OFF_W             (8 MB, exact fit; k_gather last)
#define ZB_OFF   OFF_ZQ
#define WB_OFF   (OFF_ZQ + 2097152)
#define HEN_OFF  (OFF_ZQ + 3145728)
#define CAND_OFF OFF_W

typedef __attribute__((ext_vector_type(8))) short bf16x8;
typedef __attribute__((ext_vector_type(4))) float f32x4;

__device__ inline unsigned short f2b(float f) {  // fp32 -> bf16 bits, RNE
    unsigned u = __float_as_uint(f);
    return (unsigned short)((u + 0x7FFFu + ((u >> 16) & 1u)) >> 16);
}

__device__ inline unsigned umaxu(unsigned a, unsigned b) { return a > b ? a : b; }
__device__ inline unsigned uminu(unsigned a, unsigned b) { return a < b ? a : b; }

__device__ inline void gload16(const void* g, void* l) {
    __builtin_amdgcn_global_load_lds(
        (const __attribute__((address_space(1))) unsigned int*)g,
        (__attribute__((address_space(3))) unsigned int*)l, 16, 0, 0);
}

// ---- 1. fp32 -> bf16 conversion for z and w (8 elems/thread) ----------------
__global__ void k_cvt2(const float* __restrict__ z, short* __restrict__ zb,
                       const float* __restrict__ w, short* __restrict__ wb) {
    const float* src; short* dst; size_t base;
    if (blockIdx.x < N_PTS * DIM / 2048) {
        src = z; dst = zb;
        base = (size_t)(blockIdx.x * 256 + threadIdx.x) * 8;
    } else {
        src = w; dst = wb;
        base = (size_t)((blockIdx.x - N_PTS * DIM / 2048) * 256 + threadIdx.x) * 8;
    }
    float4 a = *(const float4*)(src + base);
    float4 b = *(const float4*)(src + base + 4);
    bf16x8 o;
    o[0] = (short)f2b(a.x); o[1] = (short)f2b(a.y);
    o[2] = (short)f2b(a.z); o[3] = (short)f2b(a.w);
    o[4] = (short)f2b(b.x); o[5] = (short)f2b(b.y);
    o[6] = (short)f2b(b.z); o[7] = (short)f2b(b.w);
    *(bf16x8*)(dst + base) = o;
}

// ---- 2. half squared norms of codebook rows + zero the counters -------------
__global__ void k_enorm(const float* __restrict__ w, float* __restrict__ hen,
                        unsigned* __restrict__ cnt) {
    int gid = blockIdx.x * 256 + threadIdx.x;
    if (gid < K_CODES) cnt[gid] = 0u;
    int k    = blockIdx.x * 4 + (threadIdx.x >> 6);
    int lane = threadIdx.x & 63;
    float4 v = *(const float4*)(w + (size_t)k * DIM + lane * 4);
    float s  = v.x * v.x + v.y * v.y + v.z * v.z + v.w * v.w;
    #pragma unroll
    for (int m = 32; m >= 1; m >>= 1) s += __shfl_xor(s, m, 64);
    if (lane == 0) hen[k] = 0.5f * s;
}

// ---- 3. bf16 MFMA GEMM + top-2 candidates per (z, 128-code tile) ------------
// 128x128 tile, 4 waves (2x2 of 64x64), BK=64, 16x16x32 MFMA.
// LDS k-chunks XOR-swizzled by row&7 (swizzle applied on the GLOBAL source
// side of global_load_lds since the LDS dest must be base+lane*16).
// Keys: u32 = quantized score (1/128 steps, +2^17 bias, 18 bits) <<13 | (8191-k).
__global__ __launch_bounds__(256) void k_gemm(const short* __restrict__ zb,
                                              const short* __restrict__ wb,
                                              const float* __restrict__ hen,
                                              unsigned* __restrict__ cand) {
    __shared__ __align__(16) short smem[16384];          // 32 KB: As|Bs
    short* As = smem;
    short* Bs = smem + 8192;
    unsigned* tbuf = (unsigned*)smem;                     // reused in epilogue

    const int tid  = threadIdx.x;
    const int lane = tid & 63;
    const int wv   = tid >> 6;
    const int wm   = wv >> 1, wn = wv & 1;
    const int ztile = blockIdx.x & 127;      // kt-major: 128 blocks share B-tile
    const int kt    = blockIdx.x >> 7;
    const int z0 = ztile * 128, k0 = kt * 128;

    f32x4 acc[4][4];
    #pragma unroll
    for (int i = 0; i < 4; i++)
        #pragma unroll
        for (int j = 0; j < 4; j++) acc[i][j] = (f32x4){0.f, 0.f, 0.f, 0.f};

    const int srow = lane >> 3;                       // 0..7 within segment
    const int scol = ((lane & 7) ^ srow) * 8;         // swizzled source chunk

    // loop-invariant per-lane epilogue constants
    unsigned inv[4];
    float hc[4];
    #pragma unroll
    for (int ni = 0; ni < 4; ni++) {
        int kg = k0 + wn * 64 + ni * 16 + (lane & 15);
        inv[ni] = (unsigned)(K_CODES - 1 - kg);
        hc[ni]  = 131072.0f - 128.0f * hen[kg];
    }

    #pragma unroll
    for (int dc = 0; dc < 4; ++dc) {
        __syncthreads();
        #pragma unroll
        for (int s4 = 0; s4 < 4; ++s4) {
            int seg = wv * 4 + s4;
            gload16(zb + (size_t)(z0 + seg * 8 + srow) * DIM + dc * 64 + scol,
                    As + seg * 512 + lane * 8);
            gload16(wb + (size_t)(k0 + seg * 8 + srow) * DIM + dc * 64 + scol,
                    Bs + seg * 512 + lane * 8);
        }
        __syncthreads();
        #pragma unroll
        for (int kk = 0; kk < 2; ++kk) {
            bf16x8 af[4], bfr[4];
            int ch = ((kk << 2) + (lane >> 4)) ^ (lane & 7);   // de-swizzle
            #pragma unroll
            for (int mi = 0; mi < 4; mi++) {
                int ra = wm * 64 + mi * 16 + (lane & 15);
                af[mi] = *(const bf16x8*)&As[ra * 64 + ch * 8];
            }
            #pragma unroll
            for (int ni = 0; ni < 4; ni++) {
                int rb = wn * 64 + ni * 16 + (lane & 15);
                bfr[ni] = *(const bf16x8*)&Bs[rb * 64 + ch * 8];
            }
            #pragma unroll
            for (int mi = 0; mi < 4; mi++)
                #pragma unroll
                for (int ni = 0; ni < 4; ni++)
                    acc[mi][ni] = __builtin_amdgcn_mfma_f32_16x16x32_bf16(
                        af[mi], bfr[ni], acc[mi][ni], 0, 0, 0);
        }
    }

    __syncthreads();   // smem -> tbuf reuse

    #pragma unroll
    for (int mi = 0; mi < 4; mi++) {
        #pragma unroll
        for (int r = 0; r < 4; r++) {
            unsigned kkey[4];
            #pragma unroll
            for (int ni = 0; ni < 4; ni++) {
                unsigned q = (unsigned)fmaf(acc[mi][ni][r], 128.0f, hc[ni]);
                kkey[ni] = (q << 13) | inv[ni];
            }
            unsigned a = umaxu(kkey[0], kkey[1]), b = uminu(kkey[0], kkey[1]);
            unsigned c = umaxu(kkey[2], kkey[3]), d = uminu(kkey[2], kkey[3]);
            unsigned t1 = umaxu(a, c);
            unsigned t2 = umaxu(uminu(a, c), umaxu(b, d));
            #pragma unroll
            for (int m = 8; m >= 1; m >>= 1) {
                unsigned o1 = (unsigned)__shfl_xor((int)t1, m, 64);
                unsigned o2 = (unsigned)__shfl_xor((int)t2, m, 64);
                unsigned n1 = umaxu(t1, o1);
                t2 = umaxu(uminu(t1, o1), umaxu(t2, o2));
                t1 = n1;
            }
            if ((lane & 15) == 0) {
                int row = wm * 64 + mi * 16 + (lane >> 4) * 4 + r;
                tbuf[row * 4 + wn * 2 + 0] = t1;
                tbuf[row * 4 + wn * 2 + 1] = t2;
            }
        }
    }
    __syncthreads();
    if (tid < 128) {
        unsigned a1 = tbuf[tid * 4 + 0], a2 = tbuf[tid * 4 + 1];
        unsigned b1 = tbuf[tid * 4 + 2], b2 = tbuf[tid * 4 + 3];
        unsigned n1 = umaxu(a1, b1);
        unsigned n2 = umaxu(uminu(a1, b1), umaxu(a2, b2));
        cand[(size_t)(z0 + tid) * 128 + kt * 2 + 0] = n1;
        cand[(size_t)(z0 + tid) * 128 + kt * 2 + 1] = n2;
    }
}

// ---- 4. fp32 rescore + idx + z_q gather + loss partial + count --------------
// one wave per z-point; candidates within 96 quant-units (0.75) of max rescored
__global__ void k_rescore(const float* __restrict__ z, const float* __restrict__ w,
                          const unsigned* __restrict__ cand,
                          float* __restrict__ out,
                          unsigned* __restrict__ cnt, float* __restrict__ lossp) {
    int wid  = (blockIdx.x * 256 + threadIdx.x) >> 6;
    int lane = threadIdx.x & 63;
    float4 zv = *(const float4*)(z + (size_t)wid * DIM + lane * 4);
    uint2 cw  = *(const uint2*)(cand + (size_t)wid * 128 + lane * 2);

    unsigned mx = umaxu(cw.x, cw.y);
    #pragma unroll
    for (int m = 32; m >= 1; m >>= 1)
        mx = umaxu(mx, (unsigned)__shfl_xor((int)mx, m, 64));
    unsigned qmax = mx >> 13;
    unsigned qthr = qmax > 96u ? qmax - 96u : 0u;

    unsigned long long best = 0ULL;
    #pragma unroll
    for (int j = 0; j < 2; j++) {
        unsigned cj = j ? cw.y : cw.x;
        unsigned long long mask = __ballot((cj >> 13) >= qthr);
        while (mask) {
            int l = __ffsll((unsigned long long)mask) - 1;
            mask &= mask - 1;
            unsigned cwd = (unsigned)__shfl((int)cj, l, 64);
            int k = K_CODES - 1 - (int)(cwd & 0x1FFFu);
            float4 wv = *(const float4*)(w + (size_t)k * DIM + lane * 4);
            float s = zv.x * wv.x + zv.y * wv.y + zv.z * wv.z + zv.w * wv.w;
            float h = wv.x * wv.x + wv.y * wv.y + wv.z * wv.z + wv.w * wv.w;
            #pragma unroll
            for (int m = 32; m >= 1; m >>= 1) {
                s += __shfl_xor(s, m, 64);
                h += __shfl_xor(h, m, 64);
            }
            float sc = s - 0.5f * h;
            unsigned u = __float_as_uint(sc);
            u = (u & 0x80000000u) ? ~u : (u | 0x80000000u);
            unsigned long long key = ((unsigned long long)u << 32)
                                   | (unsigned)(K_CODES - 1 - k);
            if (key > best) best = key;
        }
    }
    int idx = K_CODES - 1 - (int)(unsigned)(best & 0xFFFFFFFFull);

    float4 wv = *(const float4*)(w + (size_t)idx * DIM + lane * 4);
    *(float4*)(out + OFF_ZQ + (size_t)wid * DIM + lane * 4) = wv;

    float dx = wv.x - zv.x, dy = wv.y - zv.y, dz = wv.z - zv.z, dw = wv.w - zv.w;
    float s2 = dx * dx + dy * dy + dz * dz + dw * dw;
    #pragma unroll
    for (int m = 32; m >= 1; m >>= 1) s2 += __shfl_xor(s2, m, 64);

    if (lane == 0) {
        out[OFF_IDX + wid] = (float)idx;
        lossp[wid] = s2;
        atomicAdd(cnt + idx, 1u);
    }
}

// ---- 5. single-block scan: offsets, cursor, new_cs, n, loss -----------------
__global__ __launch_bounds__(1024) void k_prefix(const float* __restrict__ csin,
                                                 float* __restrict__ out,
                                                 const unsigned* __restrict__ cnt,
                                                 unsigned* __restrict__ cursor,
                                                 unsigned* __restrict__ offs,
                                                 const float* __restrict__ lossp,
                                                 float* __restrict__ nval) {
    __shared__ unsigned wtot[16], wbase[16];
    __shared__ float fred[16], fred2[16];
    int t = threadIdx.x, lane = t & 63, wv = t >> 6;
    int base = t * 8;
    unsigned c[8], mysum = 0;
    #pragma unroll
    for (int i = 0; i < 8; i++) { c[i] = cnt[base + i]; mysum += c[i]; }
    unsigned inc = mysum;
    #pragma unroll
    for (int off = 1; off < 64; off <<= 1) {
        unsigned v = (unsigned)__shfl_up((int)inc, off, 64);
        if (lane >= off) inc += v;
    }
    if (lane == 63) wtot[wv] = inc;
    __syncthreads();
    if (t == 0) {
        unsigned r = 0;
        for (int i = 0; i < 16; i++) { wbase[i] = r; r += wtot[i]; }
        offs[K_CODES] = r;
    }
    __syncthreads();
    unsigned my0 = wbase[wv] + inc - mysum;
    float csl = 0.f;
    #pragma unroll
    for (int i = 0; i < 8; i++) {
        offs[base + i]   = my0;
        cursor[base + i] = my0;
        my0 += c[i];
        float ncs = DECAYF * csin[base + i] + OMDF * (float)c[i];
        out[OFF_CS + base + i] = ncs;
        csl += ncs;
    }
    #pragma unroll
    for (int m = 32; m >= 1; m >>= 1) csl += __shfl_xor(csl, m, 64);
    if (lane == 0) fred[wv] = csl;
    float lp = 0.f;
    #pragma unroll
    for (int i = 0; i < 16; i++) lp += lossp[t + i * 1024];
    #pragma unroll
    for (int m = 32; m >= 1; m >>= 1) lp += __shfl_xor(lp, m, 64);
    if (lane == 0) fred2[wv] = lp;
    __syncthreads();
    if (t == 0) {
        float n = 0.f, L = 0.f;
        for (int i = 0; i < 16; i++) { n += fred[i]; L += fred2[i]; }
        *nval = n;
        out[OFF_LOSS] = L * (1.0f / ((float)N_PTS * DIM));
    }
}

// ---- 6. fill per-code point lists -------------------------------------------
__global__ void k_fill(const float* __restrict__ out,
                       unsigned* __restrict__ cursor, unsigned* __restrict__ list) {
    int i = blockIdx.x * 256 + threadIdx.x;
    int idx = (int)out[OFF_IDX + i];
    unsigned pos = atomicAdd(cursor + idx, 1u);
    list[pos] = (unsigned)i;
}

// ---- 7. per-code gather: new_ea and new_weight rows (no atomics) ------------
__global__ void k_gather(const float* __restrict__ z, const float* __restrict__ ea,
                         float* __restrict__ out,
                         const unsigned* __restrict__ offs,
                         const unsigned* __restrict__ list,
                         const float* __restrict__ nval) {
    int k = blockIdx.x, lane = threadIdx.x;
    unsigned beg = offs[k], end = offs[k + 1];
    float4 acc = {0.f, 0.f, 0.f, 0.f};
    for (unsigned p = beg; p < end; ++p) {
        unsigned i = list[p];
        float4 zv = *(const float4*)(z + (size_t)i * DIM + lane * 4);
        acc.x += zv.x; acc.y += zv.y; acc.z += zv.z; acc.w += zv.w;
    }
    float4 e = *(const float4*)(ea + (size_t)k * DIM + lane * 4);
    e.x = DECAYF * e.x + OMDF * acc.x;
    e.y = DECAYF * e.y + OMDF * acc.y;
    e.z = DECAYF * e.z + OMDF * acc.z;
    e.w = DECAYF * e.w + OMDF * acc.w;
    *(float4*)(out + OFF_EA + (size_t)k * DIM + lane * 4) = e;

    float cs = out[OFF_CS + k];
    float n  = *nval;
    float inv = 1.f / ((cs + EPSF) / (n + (float)K_CODES * EPSF) * n);
    float4 wr = {e.x * inv, e.y * inv, e.z * inv, e.w * inv};
    *(float4*)(out + OFF_W + (size_t)k * DIM + lane * 4) = wr;
}

extern "C" void kernel_launch(void* const* d_in, const int* in_sizes, int n_in,
                              void* d_out, int out_size, void* d_ws, size_t ws_size,
                              hipStream_t stream) {
    const float* z  = (const float*)d_in[0];
    const float* w  = (const float*)d_in[1];
    const float* cs = (const float*)d_in[2];
    const float* ea = (const float*)d_in[3];
    float* out = (float*)d_out;

    short*    zb   = (short*)(out + ZB_OFF);
    short*    wb   = (short*)(out + WB_OFF);
    float*    hen  = out + HEN_OFF;
    unsigned* cand = (unsigned*)(out + CAND_OFF);

    // small scratch in d_ws (~230 KB)
    unsigned* cnt    = (unsigned*)d_ws;        // 8192
    unsigned* cursor = cnt + 8192;             // 8192
    unsigned* offs   = cursor + 8192;          // 8193 (padded to 8200)
    unsigned* list   = offs + 8200;            // 16384
    float*    lossp  = (float*)(list + 16384); // 16384
    float*    nval   = lossp + 16384;          // 1

    hipLaunchKernelGGL(k_cvt2,    dim3((N_PTS + K_CODES) * DIM / 2048), dim3(256), 0, stream,
                       z, zb, w, wb);
    hipLaunchKernelGGL(k_enorm,   dim3(K_CODES / 4),          dim3(256), 0, stream, w, hen, cnt);
    hipLaunchKernelGGL(k_gemm,    dim3((N_PTS / 128) * (K_CODES / 128)), dim3(256), 0, stream,
                       zb, wb, hen, cand);
    hipLaunchKernelGGL(k_rescore, dim3(N_PTS / 4),            dim3(256), 0, stream,
                       z, w, cand, out, cnt, lossp);
    hipLaunchKernelGGL(k_prefix,  dim3(1),                    dim3(1024), 0, stream,
                       cs, out, cnt, cursor, offs, lossp, nval);
    hipLaunchKernelGGL(k_fill,    dim3(N_PTS / 256),          dim3(256), 0, stream,
                       out, cursor, list);
    hipLaunchKernelGGL(k_gather,  dim3(K_CODES),              dim3(64), 0, stream,
                       z, ea, out, offs, list, nval);
}